// Round 1
// baseline (1075.147 us; speedup 1.0000x reference)
//
#include <hip/hip_runtime.h>

typedef unsigned short u16;
typedef unsigned int u32;
typedef __bf16 bf16x8 __attribute__((ext_vector_type(8)));
typedef float f32x4 __attribute__((ext_vector_type(4)));

__device__ __forceinline__ u16 f2bf(float f) {
  u32 u = __builtin_bit_cast(u32, f);
  return (u16)((u + 0x7fffu + ((u >> 16) & 1u)) >> 16);  // RNE
}

__device__ __forceinline__ f32x4 mfma16(bf16x8 a, bf16x8 b, f32x4 c) {
  return __builtin_amdgcn_mfma_f32_16x16x32_bf16(a, b, c, 0, 0, 0);
}

struct alignas(8) U16x4 { u16 x, y, z, w; };

// ---------------- fp32 -> bf16 convert (vectorized) ----------------
__global__ __launch_bounds__(256) void k_f32_to_bf16(const float* __restrict__ in,
                                                     u16* __restrict__ out, long n4) {
  long i = (long)blockIdx.x * blockDim.x + threadIdx.x;
  long stride = (long)gridDim.x * blockDim.x;
  for (; i < n4; i += stride) {
    float4 v = ((const float4*)in)[i];
    U16x4 o{f2bf(v.x), f2bf(v.y), f2bf(v.z), f2bf(v.w)};
    ((U16x4*)out)[i] = o;
  }
}

// ------------- transpose fp32 [rows][cols] -> bf16 [cols][rows] -------------
__global__ __launch_bounds__(256) void k_transpose_f32_to_bf16(const float* __restrict__ in,
                                                               u16* __restrict__ out,
                                                               int rows, int cols) {
  __shared__ float tile[32][33];
  int bc = blockIdx.x * 32, br = blockIdx.y * 32;
  int tx = threadIdx.x, ty = threadIdx.y;  // 32 x 8
  for (int i = 0; i < 32; i += 8)
    tile[ty + i][tx] = in[(long)(br + ty + i) * cols + bc + tx];
  __syncthreads();
  for (int i = 0; i < 32; i += 8)
    out[(long)(bc + ty + i) * rows + br + tx] = f2bf(tile[tx][ty + i]);
}

// ------------- V slice transpose: QKV[b*T+t][4096+h*128+d] -> Vt[bh][d][t] -------------
__global__ __launch_bounds__(256) void k_transpose_v(const u16* __restrict__ qkv,
                                                     u16* __restrict__ vt) {
  __shared__ u16 tile[32][33];
  int bh = blockIdx.z; int b = bh >> 4, h = bh & 15;
  int t0 = blockIdx.y * 32, d0 = blockIdx.x * 32;
  int tx = threadIdx.x, ty = threadIdx.y;  // 32 x 8
  const u16* src = qkv + (long)(b * 2048) * 6144 + 4096 + h * 128;
  for (int i = 0; i < 32; i += 8)
    tile[ty + i][tx] = src[(long)(t0 + ty + i) * 6144 + d0 + tx];
  __syncthreads();
  u16* dst = vt + (long)bh * 128 * 2048;
  for (int i = 0; i < 32; i += 8)
    dst[(long)(d0 + ty + i) * 2048 + t0 + tx] = tile[tx][ty + i];
}

// ------------- GEMM: C[M][N] = A[M][K](bf16) @ Bt[N][K](bf16)^T -------------
// 128x128 tile, BK=32, 256 thr = 4 waves (2x2), 64x64 per wave, 4x4 frags of 16x16x32.
template <typename OutT>
__global__ __launch_bounds__(256) void k_gemm_bt(const u16* __restrict__ A,
                                                 const u16* __restrict__ Bt,
                                                 OutT* __restrict__ C,
                                                 int M, int N, int K) {
  // k-subtiled LDS layout: [kg][row][8] -> fragment reads are contiguous ds_read_b128
  __shared__ alignas(16) u16 As[4][128][8];
  __shared__ alignas(16) u16 Bs[4][128][8];
  int tid = threadIdx.x;
  int lane = tid & 63;
  int wave = tid >> 6;
  int wm = (wave >> 1) * 64, wn = (wave & 1) * 64;
  int lr = lane & 15, lg = lane >> 4;
  long brow = (long)blockIdx.y * 128, bcol = (long)blockIdx.x * 128;

  f32x4 zero = {0.f, 0.f, 0.f, 0.f};
  f32x4 acc[4][4];
  for (int mi = 0; mi < 4; ++mi)
    for (int ni = 0; ni < 4; ++ni) acc[mi][ni] = zero;

  for (int k0 = 0; k0 < K; k0 += 32) {
    __syncthreads();  // previous iter's reads done before overwrite
    // stage A,B tiles: 2 x 16B per thread per matrix; 4 consecutive lanes = 64B of one row
    for (int i = 0; i < 2; ++i) {
      int c = (i << 8) + tid;
      int row = c >> 2, kq = c & 3;
      *(bf16x8*)&As[kq][row][0] = *(const bf16x8*)(A + (brow + row) * K + k0 + (kq << 3));
      *(bf16x8*)&Bs[kq][row][0] = *(const bf16x8*)(Bt + (bcol + row) * K + k0 + (kq << 3));
    }
    __syncthreads();
    bf16x8 af[4], bfr[4];
    for (int mi = 0; mi < 4; ++mi) af[mi] = *(const bf16x8*)&As[lg][wm + mi * 16 + lr][0];
    for (int ni = 0; ni < 4; ++ni) bfr[ni] = *(const bf16x8*)&Bs[lg][wn + ni * 16 + lr][0];
    for (int mi = 0; mi < 4; ++mi)
      for (int ni = 0; ni < 4; ++ni)
        acc[mi][ni] = mfma16(af[mi], bfr[ni], acc[mi][ni]);
  }
  // C/D layout: col = lane&15, row = (lane>>4)*4 + reg   [measured m89/m91]
  for (int mi = 0; mi < 4; ++mi)
    for (int ni = 0; ni < 4; ++ni)
      for (int r = 0; r < 4; ++r) {
        long row = brow + wm + mi * 16 + lg * 4 + r;
        long col = bcol + wn + ni * 16 + lr;
        float v = acc[mi][ni][r];
        if constexpr (sizeof(OutT) == 2)
          C[row * N + col] = (OutT)f2bf(v);
        else
          C[row * N + col] = v;
      }
}

// ------------- flash attention: 1 wave per 16 q-rows, kv-tile = 32 -------------
// QKV: [8192][6144] bf16 (q|k|v thirds, head h at col h*128 within each third)
// Vt:  [64][128][2048] bf16 (d-major per (b,h))
// Y:   [8192][2048] bf16
__global__ __launch_bounds__(64) void k_attn(const u16* __restrict__ qkv,
                                             const u16* __restrict__ vt,
                                             u16* __restrict__ y) {
  int qt = blockIdx.x;              // 0..127
  int bh = blockIdx.y;              // 0..63
  int b = bh >> 4, h = bh & 15;
  int lane = threadIdx.x;
  int lr = lane & 15, lg = lane >> 4;
  __shared__ alignas(16) u16 plds[16][32];
  const float scale = 0.08838834764831845f;  // 1/sqrt(128)

  // Q fragments (B-operand of swapped QK^T): lane lr = q row, lg = d-subgroup
  const u16* qbase = qkv + (long)(b * 2048 + qt * 16) * 6144 + h * 128;
  bf16x8 qf[4];
  for (int dc = 0; dc < 4; ++dc)
    qf[dc] = *(const bf16x8*)(qbase + (long)lr * 6144 + dc * 32 + lg * 8);

  const u16* kbase = qkv + (long)(b * 2048) * 6144 + 2048 + h * 128;
  const u16* vbase = vt + (long)bh * 128 * 2048;

  float m_run = -1e30f, l_run = 0.f;
  f32x4 zero = {0.f, 0.f, 0.f, 0.f};
  f32x4 o[8];
  for (int i = 0; i < 8; ++i) o[i] = zero;

  int q_glob = qt * 16 + lr;
  int ktiles = (qt * 16 + 15) / 32 + 1;

  for (int kt = 0; kt < ktiles; ++kt) {
    // S^T = mfma(K, Q): D[m=key][n=q]; two 16-key halves
    f32x4 s0 = zero, s1 = zero;
    for (int dc = 0; dc < 4; ++dc) {
      bf16x8 kf0 = *(const bf16x8*)(kbase + (long)(kt * 32 + lr) * 6144 + dc * 32 + lg * 8);
      bf16x8 kf1 = *(const bf16x8*)(kbase + (long)(kt * 32 + 16 + lr) * 6144 + dc * 32 + lg * 8);
      s0 = mfma16(kf0, qf[dc], s0);
      s1 = mfma16(kf1, qf[dc], s1);
    }
    // lane holds S[keys kt*32 + {lg*4+r, 16+lg*4+r}][q = lr]
    float p[8];
    float tmax = -1e30f;
    for (int r = 0; r < 4; ++r) {
      int key0 = kt * 32 + lg * 4 + r;
      int key1 = key0 + 16;
      float v0 = (key0 <= q_glob) ? s0[r] * scale : -1e30f;
      float v1 = (key1 <= q_glob) ? s1[r] * scale : -1e30f;
      p[r] = v0; p[4 + r] = v1;
      tmax = fmaxf(tmax, fmaxf(v0, v1));
    }
    tmax = fmaxf(tmax, __shfl_xor(tmax, 16));
    tmax = fmaxf(tmax, __shfl_xor(tmax, 32));
    float m_new = fmaxf(m_run, tmax);
    float alpha = __expf(m_run - m_new);
    float psum = 0.f;
    for (int i = 0; i < 8; ++i) { p[i] = __expf(p[i] - m_new); psum += p[i]; }
    psum += __shfl_xor(psum, 16);
    psum += __shfl_xor(psum, 32);
    l_run = l_run * alpha + psum;
    m_run = m_new;

    // P -> LDS (P[q][key_local]), re-fragment for PV A-operand
    U16x4 pk0{f2bf(p[0]), f2bf(p[1]), f2bf(p[2]), f2bf(p[3])};
    U16x4 pk1{f2bf(p[4]), f2bf(p[5]), f2bf(p[6]), f2bf(p[7])};
    *(U16x4*)&plds[lr][lg * 4] = pk0;
    *(U16x4*)&plds[lr][16 + lg * 4] = pk1;
    __syncthreads();  // single wave: forces lgkmcnt drain
    bf16x8 pf = *(const bf16x8*)&plds[lr][lg * 8];

    // rescale O by alpha of its own q-rows (O rows are q = lg*4+r)
    float alr[4];
    for (int r = 0; r < 4; ++r) alr[r] = __shfl(alpha, lg * 4 + r);
    for (int i = 0; i < 8; ++i)
      for (int r = 0; r < 4; ++r) o[i][r] *= alr[r];

    // PV: D[m=q][n=d], B-operand from Vt rows (d-major)
    for (int i = 0; i < 8; ++i) {
      bf16x8 vf = *(const bf16x8*)(vbase + (long)(i * 16 + lr) * 2048 + kt * 32 + lg * 8);
      o[i] = mfma16(pf, vf, o[i]);
    }
    __syncthreads();  // reads of plds done before next iter's writes
  }

  float linv[4];
  for (int r = 0; r < 4; ++r) {
    float lv = __shfl(l_run, lg * 4 + r);
    linv[r] = 1.0f / lv;
  }
  u16* ybase = y + (long)(b * 2048 + qt * 16) * 2048 + h * 128;
  for (int i = 0; i < 8; ++i)
    for (int r = 0; r < 4; ++r)
      ybase[(long)(lg * 4 + r) * 2048 + i * 16 + lr] = f2bf(o[i][r] * linv[r]);
}

// ------------------------------- launch -------------------------------
extern "C" void kernel_launch(void* const* d_in, const int* in_sizes, int n_in,
                              void* d_out, int out_size, void* d_ws, size_t ws_size,
                              hipStream_t stream) {
  const float* x = (const float*)d_in[0];       // [4,2048,2048]
  const float* w_qkv = (const float*)d_in[1];   // [2048,6144]
  const float* w_proj = (const float*)d_in[2];  // [2048,2048]
  float* out = (float*)d_out;                   // [4,2048,2048] fp32

  char* ws = (char*)d_ws;
  // ws layout (bytes):
  //   QKV  [8192][6144] bf16 : 100663296
  //   WqT  [6144][2048] bf16 :  25165824
  //   WpT  [2048][2048] bf16 :   8388608
  //   Xb/Y [8192][2048] bf16 :  33554432   (Xb consumed by GEMM1, then reused for Y)
  //   Vt   [64][128][2048]   :  33554432
  if (ws_size < 201326592ull) return;
  u16* QKV = (u16*)(ws);
  u16* WqT = (u16*)(ws + 100663296);
  u16* WpT = (u16*)(ws + 125829120);
  u16* Xb  = (u16*)(ws + 134217728);
  u16* Vt  = (u16*)(ws + 167772160);

  dim3 tb32x8(32, 8);

  k_f32_to_bf16<<<2048, 256, 0, stream>>>(x, Xb, (8192L * 2048) / 4);
  k_transpose_f32_to_bf16<<<dim3(192, 64), tb32x8, 0, stream>>>(w_qkv, WqT, 2048, 6144);
  k_transpose_f32_to_bf16<<<dim3(64, 64), tb32x8, 0, stream>>>(w_proj, WpT, 2048, 2048);

  k_gemm_bt<u16><<<dim3(48, 64), 256, 0, stream>>>(Xb, WqT, QKV, 8192, 6144, 2048);

  k_transpose_v<<<dim3(4, 64, 64), tb32x8, 0, stream>>>(QKV, Vt);

  k_attn<<<dim3(128, 64), 64, 0, stream>>>(QKV, Vt, Xb /* Y */);

  k_gemm_bt<float><<<dim3(16, 64), 256, 0, stream>>>(Xb, WpT, out, 8192, 2048, 2048);
}

// Round 2
// 567.864 us; speedup vs baseline: 1.8933x; 1.8933x over previous
//
#include <hip/hip_runtime.h>

typedef unsigned short u16;
typedef unsigned int u32;
typedef __bf16 bf16x8 __attribute__((ext_vector_type(8)));
typedef float f32x4 __attribute__((ext_vector_type(4)));

__device__ __forceinline__ u16 f2bf(float f) {
  u32 u = __builtin_bit_cast(u32, f);
  return (u16)((u + 0x7fffu + ((u >> 16) & 1u)) >> 16);  // RNE
}

__device__ __forceinline__ f32x4 mfma16(bf16x8 a, bf16x8 b, f32x4 c) {
  return __builtin_amdgcn_mfma_f32_16x16x32_bf16(a, b, c, 0, 0, 0);
}

struct alignas(8) U16x4 { u16 x, y, z, w; };

#define AS1 __attribute__((address_space(1)))
#define AS3 __attribute__((address_space(3)))
// async global->LDS, 16B per lane; lds dest = wave-uniform base + lane*16
__device__ __forceinline__ void gl16(const u16* g, u16* l) {
  __builtin_amdgcn_global_load_lds((const AS1 u32*)g, (AS3 u32*)l, 16, 0, 0);
}

// ---------------- fp32 -> bf16 convert (vectorized) ----------------
__global__ __launch_bounds__(256) void k_f32_to_bf16(const float* __restrict__ in,
                                                     u16* __restrict__ out, long n4) {
  long i = (long)blockIdx.x * blockDim.x + threadIdx.x;
  long stride = (long)gridDim.x * blockDim.x;
  for (; i < n4; i += stride) {
    float4 v = ((const float4*)in)[i];
    U16x4 o{f2bf(v.x), f2bf(v.y), f2bf(v.z), f2bf(v.w)};
    ((U16x4*)out)[i] = o;
  }
}

// ------------- transpose fp32 [rows][cols] -> bf16 [cols][rows] -------------
__global__ __launch_bounds__(256) void k_transpose_f32_to_bf16(const float* __restrict__ in,
                                                               u16* __restrict__ out,
                                                               int rows, int cols) {
  __shared__ float tile[32][33];
  int bc = blockIdx.x * 32, br = blockIdx.y * 32;
  int tx = threadIdx.x, ty = threadIdx.y;  // 32 x 8
  for (int i = 0; i < 32; i += 8)
    tile[ty + i][tx] = in[(long)(br + ty + i) * cols + bc + tx];
  __syncthreads();
  for (int i = 0; i < 32; i += 8)
    out[(long)(bc + ty + i) * rows + br + tx] = f2bf(tile[tx][ty + i]);
}

// ------------- V slice transpose: QKV[b*T+t][4096+h*128+d] -> Vt[bh][d][t] -------------
__global__ __launch_bounds__(256) void k_transpose_v(const u16* __restrict__ qkv,
                                                     u16* __restrict__ vt) {
  __shared__ u16 tile[32][33];
  int bh = blockIdx.z; int b = bh >> 4, h = bh & 15;
  int t0 = blockIdx.y * 32, d0 = blockIdx.x * 32;
  int tx = threadIdx.x, ty = threadIdx.y;  // 32 x 8
  const u16* src = qkv + (long)(b * 2048) * 6144 + 4096 + h * 128;
  for (int i = 0; i < 32; i += 8)
    tile[ty + i][tx] = src[(long)(t0 + ty + i) * 6144 + d0 + tx];
  __syncthreads();
  u16* dst = vt + (long)bh * 128 * 2048;
  for (int i = 0; i < 32; i += 8)
    dst[(long)(d0 + ty + i) * 2048 + t0 + tx] = tile[tx][ty + i];
}

// ------------- GEMM: C[M][N] = A[M][K](bf16) @ Bt[N][K](bf16)^T -------------
template <typename OutT>
__global__ __launch_bounds__(256) void k_gemm_bt(const u16* __restrict__ A,
                                                 const u16* __restrict__ Bt,
                                                 OutT* __restrict__ C,
                                                 int M, int N, int K) {
  __shared__ alignas(16) u16 As[4][128][8];
  __shared__ alignas(16) u16 Bs[4][128][8];
  int tid = threadIdx.x;
  int lane = tid & 63;
  int wave = tid >> 6;
  int wm = (wave >> 1) * 64, wn = (wave & 1) * 64;
  int lr = lane & 15, lg = lane >> 4;
  long brow = (long)blockIdx.y * 128, bcol = (long)blockIdx.x * 128;

  f32x4 zero = {0.f, 0.f, 0.f, 0.f};
  f32x4 acc[4][4];
  for (int mi = 0; mi < 4; ++mi)
    for (int ni = 0; ni < 4; ++ni) acc[mi][ni] = zero;

  for (int k0 = 0; k0 < K; k0 += 32) {
    __syncthreads();
    for (int i = 0; i < 2; ++i) {
      int c = (i << 8) + tid;
      int row = c >> 2, kq = c & 3;
      *(bf16x8*)&As[kq][row][0] = *(const bf16x8*)(A + (brow + row) * K + k0 + (kq << 3));
      *(bf16x8*)&Bs[kq][row][0] = *(const bf16x8*)(Bt + (bcol + row) * K + k0 + (kq << 3));
    }
    __syncthreads();
    bf16x8 af[4], bfr[4];
    for (int mi = 0; mi < 4; ++mi) af[mi] = *(const bf16x8*)&As[lg][wm + mi * 16 + lr][0];
    for (int ni = 0; ni < 4; ++ni) bfr[ni] = *(const bf16x8*)&Bs[lg][wn + ni * 16 + lr][0];
    for (int mi = 0; mi < 4; ++mi)
      for (int ni = 0; ni < 4; ++ni)
        acc[mi][ni] = mfma16(af[mi], bfr[ni], acc[mi][ni]);
  }
  for (int mi = 0; mi < 4; ++mi)
    for (int ni = 0; ni < 4; ++ni)
      for (int r = 0; r < 4; ++r) {
        long row = brow + wm + mi * 16 + lg * 4 + r;
        long col = bcol + wn + ni * 16 + lr;
        float v = acc[mi][ni][r];
        if constexpr (sizeof(OutT) == 2)
          C[row * N + col] = (OutT)f2bf(v);
        else
          C[row * N + col] = v;
      }
}

// ------------- flash attention v2: 4 waves x 32 q-rows, KV tile 64, LDS dbuf -------------
// QKV: [8192][6144] bf16; Vt: [64][128][2048] bf16 (d-major); Y: [8192][2048] bf16
// Grid: x = bh (64), y = 16 (qb = 15 - y, heavy tiles dispatched first)
__global__ __launch_bounds__(256, 2) void k_attn2(const u16* __restrict__ qkv,
                                                  const u16* __restrict__ vt,
                                                  u16* __restrict__ y) {
  __shared__ alignas(16) u16 Ks[2][64 * 128];   // [row t][chunk-swizzled d], 16KB each
  __shared__ alignas(16) u16 Vs[2][128 * 64];   // [row d][chunk-swizzled t], 16KB each
  __shared__ alignas(16) u16 Ps[4][32 * 64];    // per-wave P, swizzled, 4KB each

  int bh = blockIdx.x;
  int qb = 15 - (int)blockIdx.y;
  int b = bh >> 4, h = bh & 15;
  int tid = threadIdx.x;
  int lane = tid & 63;
  int w = tid >> 6;
  int lr = lane & 15, lg = lane >> 4;
  int x7 = lr & 7;
  const float scale = 0.08838834764831845f;  // 1/sqrt(128)

  const u16* kbase = qkv + (long)(b * 2048) * 6144 + 2048 + h * 128;
  const u16* vtbh = vt + (long)bh * 128 * 2048;
  int qbase = qb * 128 + w * 32;

  // Q fragments (B-operand of swapped QK^T): lane lr = q row, lg = d-subgroup
  const u16* qptr = qkv + (long)(qb * 128 + b * 2048) * 6144 + h * 128;
  bf16x8 qf[2][4];
  for (int qsub = 0; qsub < 2; ++qsub)
    for (int dc = 0; dc < 4; ++dc)
      qf[qsub][dc] = *(const bf16x8*)(qptr + (long)(w * 32 + qsub * 16 + lr) * 6144 + dc * 32 + lg * 8);

  f32x4 zero = {0.f, 0.f, 0.f, 0.f};
  f32x4 o[2][8];
  for (int qs = 0; qs < 2; ++qs)
    for (int ds = 0; ds < 8; ++ds) o[qs][ds] = zero;
  float m_run[2] = {-1e30f, -1e30f};
  float l_run[2] = {0.f, 0.f};

  int nkt = 2 * qb + 2;
  int qmaxw = qbase + 31;
  u16* Pw = &Ps[w][0];

#define STAGE(BUF, KT)                                                          \
  do {                                                                          \
    for (int i_ = 0; i_ < 4; ++i_) {                                            \
      int rl_ = w * 16 + i_ * 4;                                                \
      int row_ = rl_ + (lane >> 4);                                             \
      int ch_ = (lane & 15) ^ (row_ & 7);                                       \
      gl16(kbase + (long)((KT)*64 + row_) * 6144 + ch_ * 8, &Ks[BUF][rl_ * 128]); \
    }                                                                           \
    for (int i_ = 0; i_ < 4; ++i_) {                                            \
      int dl_ = w * 32 + i_ * 8;                                                \
      int d_ = dl_ + (lane >> 3);                                               \
      int ch_ = (lane & 7) ^ (d_ & 7);                                          \
      gl16(vtbh + (long)d_ * 2048 + (KT)*64 + ch_ * 8, &Vs[BUF][dl_ * 64]);     \
    }                                                                           \
  } while (0)

#define COMPUTE(BUF, KT)                                                        \
  do {                                                                          \
    const u16* Kb = &Ks[BUF][0];                                                \
    const u16* Vb = &Vs[BUF][0];                                                \
    f32x4 s[2][4];                                                              \
    for (int qs = 0; qs < 2; ++qs)                                              \
      for (int ks = 0; ks < 4; ++ks) s[qs][ks] = zero;                          \
    for (int ks = 0; ks < 4; ++ks) {                                            \
      int row = ks * 16 + lr;                                                   \
      for (int dc = 0; dc < 4; ++dc) {                                          \
        bf16x8 kf = *(const bf16x8*)(Kb + row * 128 + ((dc * 4 + lg) ^ x7) * 8); \
        s[0][ks] = mfma16(kf, qf[0][dc], s[0][ks]);                             \
        s[1][ks] = mfma16(kf, qf[1][dc], s[1][ks]);                             \
      }                                                                         \
    }                                                                           \
    for (int qs = 0; qs < 2; ++qs) {                                            \
      int qg = qbase + qs * 16 + lr;                                            \
      float p[16];                                                              \
      float tmax = -1e30f;                                                      \
      for (int ks = 0; ks < 4; ++ks)                                            \
        for (int r = 0; r < 4; ++r) {                                           \
          int key = (KT)*64 + ks * 16 + lg * 4 + r;                             \
          float v = (key <= qg) ? s[qs][ks][r] * scale : -1e30f;                \
          p[ks * 4 + r] = v;                                                    \
          tmax = fmaxf(tmax, v);                                                \
        }                                                                       \
      tmax = fmaxf(tmax, __shfl_xor(tmax, 16));                                 \
      tmax = fmaxf(tmax, __shfl_xor(tmax, 32));                                 \
      float m_new = fmaxf(m_run[qs], tmax);                                     \
      float alpha = __expf(m_run[qs] - m_new);                                  \
      float psum = 0.f;                                                         \
      for (int i = 0; i < 16; ++i) {                                            \
        p[i] = __expf(p[i] - m_new);                                            \
        psum += p[i];                                                           \
      }                                                                         \
      psum += __shfl_xor(psum, 16);                                             \
      psum += __shfl_xor(psum, 32);                                             \
      l_run[qs] = l_run[qs] * alpha + psum;                                     \
      m_run[qs] = m_new;                                                        \
      int prow = qs * 16 + lr;                                                  \
      for (int ks = 0; ks < 4; ++ks) {                                          \
        U16x4 pk{f2bf(p[ks * 4 + 0]), f2bf(p[ks * 4 + 1]),                      \
                 f2bf(p[ks * 4 + 2]), f2bf(p[ks * 4 + 3])};                     \
        int chunk = ks * 2 + (lg >> 1);                                         \
        *(U16x4*)&Pw[prow * 64 + ((chunk ^ x7) * 8) + (lg & 1) * 4] = pk;       \
      }                                                                         \
      float alr[4];                                                             \
      for (int r = 0; r < 4; ++r) alr[r] = __shfl(alpha, lg * 4 + r);           \
      for (int ds = 0; ds < 8; ++ds)                                            \
        for (int r = 0; r < 4; ++r) o[qs][ds][r] *= alr[r];                     \
    }                                                                           \
    asm volatile("s_waitcnt lgkmcnt(0)" ::: "memory");                          \
    for (int j = 0; j < 2; ++j) {                                               \
      int chv = ((j * 4 + lg) ^ x7) * 8;                                        \
      bf16x8 pa0 = *(const bf16x8*)&Pw[(0 * 16 + lr) * 64 + chv];               \
      bf16x8 pa1 = *(const bf16x8*)&Pw[(1 * 16 + lr) * 64 + chv];               \
      for (int ds = 0; ds < 8; ++ds) {                                          \
        bf16x8 vf = *(const bf16x8*)(Vb + (ds * 16 + lr) * 64 + chv);           \
        o[0][ds] = mfma16(pa0, vf, o[0][ds]);                                   \
        o[1][ds] = mfma16(pa1, vf, o[1][ds]);                                   \
      }                                                                         \
    }                                                                           \
  } while (0)

  int buf = 0;
  STAGE(0, 0);
  asm volatile("s_waitcnt vmcnt(0)" ::: "memory");
  __builtin_amdgcn_s_barrier();
  for (int kt = 0; kt < nkt - 1; ++kt) {
    STAGE(buf ^ 1, kt + 1);
    if (kt * 64 <= qmaxw) COMPUTE(buf, kt);
    asm volatile("s_waitcnt vmcnt(0) lgkmcnt(0)" ::: "memory");
    __builtin_amdgcn_s_barrier();
    buf ^= 1;
  }
  {
    int kt = nkt - 1;
    if (kt * 64 <= qmaxw) COMPUTE(buf, kt);
  }
#undef STAGE
#undef COMPUTE

  float linv[2][4];
  for (int qs = 0; qs < 2; ++qs)
    for (int r = 0; r < 4; ++r) linv[qs][r] = 1.0f / __shfl(l_run[qs], lg * 4 + r);
  u16* yb = y + (long)(b * 2048 + qb * 128 + w * 32) * 2048 + h * 128;
  for (int qs = 0; qs < 2; ++qs)
    for (int ds = 0; ds < 8; ++ds)
      for (int r = 0; r < 4; ++r)
        yb[(long)(qs * 16 + lg * 4 + r) * 2048 + ds * 16 + lr] = f2bf(o[qs][ds][r] * linv[qs][r]);
}

// ------------------------------- launch -------------------------------
extern "C" void kernel_launch(void* const* d_in, const int* in_sizes, int n_in,
                              void* d_out, int out_size, void* d_ws, size_t ws_size,
                              hipStream_t stream) {
  const float* x = (const float*)d_in[0];       // [4,2048,2048]
  const float* w_qkv = (const float*)d_in[1];   // [2048,6144]
  const float* w_proj = (const float*)d_in[2];  // [2048,2048]
  float* out = (float*)d_out;                   // [4,2048,2048] fp32

  char* ws = (char*)d_ws;
  if (ws_size < 201326592ull) return;
  u16* QKV = (u16*)(ws);
  u16* WqT = (u16*)(ws + 100663296);
  u16* WpT = (u16*)(ws + 125829120);
  u16* Xb  = (u16*)(ws + 134217728);
  u16* Vt  = (u16*)(ws + 167772160);

  dim3 tb32x8(32, 8);

  k_f32_to_bf16<<<2048, 256, 0, stream>>>(x, Xb, (8192L * 2048) / 4);
  k_transpose_f32_to_bf16<<<dim3(192, 64), tb32x8, 0, stream>>>(w_qkv, WqT, 2048, 6144);
  k_transpose_f32_to_bf16<<<dim3(64, 64), tb32x8, 0, stream>>>(w_proj, WpT, 2048, 2048);

  k_gemm_bt<u16><<<dim3(48, 64), 256, 0, stream>>>(Xb, WqT, QKV, 8192, 6144, 2048);

  k_transpose_v<<<dim3(4, 64, 64), tb32x8, 0, stream>>>(QKV, Vt);

  k_attn2<<<dim3(64, 16), 256, 0, stream>>>(QKV, Vt, Xb /* Y */);

  k_gemm_bt<float><<<dim3(16, 64), 256, 0, stream>>>(Xb, WpT, out, 8192, 2048, 2048);
}